// Round 5
// baseline (1244.214 us; speedup 1.0000x reference)
//
#include <hip/hip_runtime.h>
#include <hip/hip_bf16.h>
#include <math.h>

#define N_RESC 10000
#define N_EDGEC 320000
#define C_SC 384
#define C_ZC 128
#define AGG_D 864
#define FEAT_D 960
#define OUT_D 384
#define NPAD 10240   /* padded node dim for transposed layouts */

// scales
#define S1C 0.14433756729740643f   /* sqrt(1/48) */
#define S2C 0.5773502691896258f    /* sqrt(1/3)  */
#define SHWC 0.13608276348795434f  /* sqrt(1/54) */

__global__ void k_zero(int* cursor) {
    int i = blockIdx.x * 256 + threadIdx.x;
    if (i < N_RESC) cursor[i] = 0;
}

__global__ void k_hist(const int* __restrict__ ei, int* cursor) {
    int e = blockIdx.x * 256 + threadIdx.x;
    if (e < N_EDGEC) atomicAdd(&cursor[ei[N_EDGEC + e]], 1);
}

__global__ __launch_bounds__(1024) void k_scan(int* cursor, int* rowptr) {
    __shared__ int buf[1024];
    __shared__ int carry_s;
    int t = threadIdx.x;
    if (t == 0) carry_s = 0;
    __syncthreads();
    for (int ch = 0; ch < 10; ++ch) {
        int idx = ch * 1024 + t;
        int v = (idx < N_RESC) ? cursor[idx] : 0;
        buf[t] = v;
        __syncthreads();
        for (int off = 1; off < 1024; off <<= 1) {
            int x = (t >= off) ? buf[t - off] : 0;
            __syncthreads();
            buf[t] += x;
            __syncthreads();
        }
        int incl = buf[t];
        int excl = incl - v;
        int base = carry_s;
        int total = buf[1023];
        if (idx < N_RESC) { rowptr[idx] = base + excl; cursor[idx] = base + excl; }
        __syncthreads();
        if (t == 0) carry_s = base + total;
        __syncthreads();
    }
    if (t == 0) rowptr[N_RESC] = carry_s;
}

__global__ void k_scatter(const int* __restrict__ ei, int* cursor, int* csr, int* src_csr) {
    int e = blockIdx.x * 256 + threadIdx.x;
    if (e < N_EDGEC) {
        int d = ei[N_EDGEC + e];
        int s = ei[e];
        int pos = atomicAdd(&cursor[d], 1);
        csr[pos] = e;
        src_csr[pos] = s;
    }
}

// ---- pack [wq|wkv|wqp|wkvp] into W_all[384][1152], biases into b_all[1152] ----
__global__ void k_pack(const float* __restrict__ wq, const float* __restrict__ wkv,
                       const float* __restrict__ wqp, const float* __restrict__ wkvp,
                       const float* __restrict__ bq, const float* __restrict__ bkv,
                       const float* __restrict__ bqp, const float* __restrict__ bkvp,
                       float* __restrict__ W_all, float* __restrict__ b_all) {
    long idx = (long)blockIdx.x * 256 + threadIdx.x;
    if (idx >= 384L * 1152) return;
    int j = (int)(idx / 1152), c = (int)(idx % 1152);
    float v;
    if (c < 192)      v = wq[j * 192 + c];
    else if (c < 576) v = wkv[j * 384 + (c - 192)];
    else if (c < 720) v = wqp[j * 144 + (c - 576)];
    else              v = wkvp[j * 432 + (c - 720)];
    W_all[idx] = v;
    if (j == 0) {
        float b;
        if (c < 192)      b = bq[c];
        else if (c < 576) b = bkv[c - 192];
        else if (c < 720) b = bqp[c - 576];
        else              b = bkvp[c - 720];
        b_all[c] = b;
    }
}

// ---- transpose s (10000x384) -> sT (384 x NPAD) ----
__global__ __launch_bounds__(256) void k_transpose(const float* __restrict__ s,
                                                   float* __restrict__ sT) {
    __shared__ float tile[64][65];
    int n0 = blockIdx.x * 64;
    int j0 = blockIdx.y * 64;
    int t = threadIdx.x;
    int c = t & 63, r4 = t >> 6;
    #pragma unroll
    for (int i = 0; i < 16; i++) {
        int r = i * 4 + r4;
        int n = n0 + r;
        tile[r][c] = (n < N_RESC) ? s[(long)n * C_SC + j0 + c] : 0.f;
    }
    __syncthreads();
    #pragma unroll
    for (int i = 0; i < 16; i++) {
        int r = i * 4 + r4;   // feature row within tile
        sT[(long)(j0 + r) * NPAD + n0 + c] = tile[c][r];
    }
}

// ---- node projection GEMM: lane=node, wave-uniform weight cols ----
// grid (157, 9); block 256 = 4 waves; wave handles 32 cols x 64 nodes; K=384
__global__ __launch_bounds__(256) void k_proj_g(const float* __restrict__ sT,
    const float* __restrict__ W_all, const float* __restrict__ b_all,
    float* __restrict__ qh, float* __restrict__ kh, float* __restrict__ vh,
    float* __restrict__ praw) {
    int t = threadIdx.x;
    int lane = t & 63;
    int wv = __builtin_amdgcn_readfirstlane(t >> 6);
    int n = blockIdx.x * 64 + lane;
    int c0 = blockIdx.y * 128 + wv * 32;
    float acc[32];
    #pragma unroll
    for (int cc = 0; cc < 32; cc++) acc[cc] = b_all[c0 + cc];
    const float* wbase = W_all + c0;
    for (int j = 0; j < C_SC; j++) {
        float sval = sT[(long)j * NPAD + n];
        const float* wj = wbase + (long)j * 1152;
        #pragma unroll
        for (int q = 0; q < 8; q++) {
            float4 w4 = *(const float4*)(wj + q * 4);
            acc[q*4+0] = fmaf(sval, w4.x, acc[q*4+0]);
            acc[q*4+1] = fmaf(sval, w4.y, acc[q*4+1]);
            acc[q*4+2] = fmaf(sval, w4.z, acc[q*4+2]);
            acc[q*4+3] = fmaf(sval, w4.w, acc[q*4+3]);
        }
    }
    if (n < N_RESC) {
        #pragma unroll
        for (int cc = 0; cc < 32; cc++) {
            int c = c0 + cc;
            float val = acc[cc];
            if (c < 192) qh[(long)n * 192 + c] = val;
            else if (c < 576) {
                int d = c - 192; int h = d >> 5, r = d & 31;
                if (r < 16) kh[(long)n * 192 + h * 16 + r] = val;
                else        vh[(long)n * 192 + h * 16 + (r - 16)] = val;
            } else praw[(long)n * 576 + (c - 576)] = val;
        }
    }
}

// ---- rotate/translate raw point projections into global frame, split layouts ----
__global__ __launch_bounds__(192) void k_rot(const float* __restrict__ praw,
    const float* __restrict__ rot, const float* __restrict__ trans,
    float* __restrict__ qpts, float* __restrict__ kpts, float* __restrict__ vpts) {
    int n = blockIdx.x;
    int t = threadIdx.x;
    __shared__ float R[9], T[3];
    if (t < 9) R[t] = rot[n * 9 + t];
    if (t < 3) T[t] = trans[n * 3 + t];
    __syncthreads();
    const float* pr = praw + (long)n * 576;
    if (t < 48) {
        float x0 = pr[t], x1 = pr[48 + t], x2 = pr[96 + t];
        #pragma unroll
        for (int i = 0; i < 3; i++)
            qpts[(long)n * 144 + t * 3 + i] = R[i*3+0]*x0 + R[i*3+1]*x1 + R[i*3+2]*x2 + T[i];
    } else {
        int p = t - 48;   // 0..143 = h*12+pp
        float x0 = pr[144 + p], x1 = pr[288 + p], x2 = pr[432 + p];
        int h = p / 12, pp = p % 12;
        #pragma unroll
        for (int i = 0; i < 3; i++) {
            float val = R[i*3+0]*x0 + R[i*3+1]*x1 + R[i*3+2]*x2 + T[i];
            if (pp < 4) kpts[(long)n * 144 + (h * 4 + pp) * 3 + i] = val;
            else        vpts[(long)n * 288 + (h * 8 + (pp - 4)) * 3 + i] = val;
        }
    }
}

// ---- edge GEMM: [b_e | pairz] = z @ [wb | wdz] + bias ----
__global__ __launch_bounds__(256) void k_zproj(const float* __restrict__ z,
    const float* __restrict__ wb, const float* __restrict__ bb,
    const float* __restrict__ wdz, const float* __restrict__ bdz,
    float* __restrict__ b_e, float* __restrict__ pairz) {
    int t = threadIdx.x;
    long e = (long)blockIdx.x * 256 + t;
    float acc[44];
    #pragma unroll
    for (int c = 0; c < 12; c++) acc[c] = bb[c];
    #pragma unroll
    for (int c = 0; c < 32; c++) acc[12 + c] = bdz[c];
    const float4* zrow = reinterpret_cast<const float4*>(z + e * C_ZC);
    for (int j4 = 0; j4 < 32; j4++) {
        float4 zv = zrow[j4];
        #pragma unroll
        for (int u = 0; u < 4; u++) {
            float zs = (u == 0) ? zv.x : (u == 1) ? zv.y : (u == 2) ? zv.z : zv.w;
            int j = j4 * 4 + u;
            #pragma unroll
            for (int c = 0; c < 12; c++) acc[c] = fmaf(zs, wb[j * 12 + c], acc[c]);
            #pragma unroll
            for (int c = 0; c < 32; c++) acc[12 + c] = fmaf(zs, wdz[j * 32 + c], acc[12 + c]);
        }
    }
    float4* bo = reinterpret_cast<float4*>(b_e + e * 12);
    #pragma unroll
    for (int q = 0; q < 3; q++)
        bo[q] = make_float4(acc[q*4], acc[q*4+1], acc[q*4+2], acc[q*4+3]);
    float4* po = reinterpret_cast<float4*>(pairz + e * 32);
    #pragma unroll
    for (int q = 0; q < 8; q++)
        po[q] = make_float4(acc[12+q*4], acc[12+q*4+1], acc[12+q*4+2], acc[12+q*4+3]);
}

// ---- logits in CSR (dst) order: q staged per node, dense k gathers ----
__global__ __launch_bounds__(256) void k_logit(const int* __restrict__ rowptr,
    const int* __restrict__ csr, const int* __restrict__ src_csr,
    const float* __restrict__ qh, const float* __restrict__ kh,
    const float* __restrict__ qpts, const float* __restrict__ kpts,
    const float* __restrict__ mask, const float* __restrict__ head_w,
    const float* __restrict__ b_e, float* __restrict__ alog) {
    int n = blockIdx.x;
    int t = threadIdx.x;
    __shared__ float qf[192], qp[144], hws[12];
    if (t < 192) qf[t] = qh[(long)n * 192 + t];
    if (t < 144) qp[t] = qpts[(long)n * 144 + t];
    if (t < 12)  hws[t] = log1pf(expf(head_w[t])) * SHWC;
    float mdst = mask[n];
    __syncthreads();
    int row0 = rowptr[n];
    int deg = rowptr[n + 1] - row0;
    int w = t >> 6, l = t & 63, c = l & 15, hq = l >> 4;
    for (int i = w; i < deg; i += 4) {
        int pos = row0 + i;
        int src = src_csr[pos];
        int e = csr[pos];
        float em = 100000.0f * (mask[src] * mdst - 1.0f);
        #pragma unroll
        for (int tp = 0; tp < 3; tp++) {
            int h = tp * 4 + hq;
            float val = S1C * qf[h * 16 + c] * kh[(long)src * 192 + tp * 64 + l];
            if (c < 12) {
                float d = qp[h * 12 + c] - kpts[(long)src * 144 + h * 12 + c];
                val = fmaf(-0.5f * hws[h] * d, d, val);
            }
            val += __shfl_xor(val, 8, 16);
            val += __shfl_xor(val, 4, 16);
            val += __shfl_xor(val, 2, 16);
            val += __shfl_xor(val, 1, 16);
            if (c == 0) alog[(long)pos * 12 + h] = val + S2C * b_e[(long)e * 12 + h] + em;
        }
    }
}

// ---- per-node segment softmax + weighted aggregation -> featsT (transposed) ----
#define CAPE 256
__global__ __launch_bounds__(256) void k_agg(const int* __restrict__ rowptr,
    const int* __restrict__ csr, const int* __restrict__ src_csr,
    const float* __restrict__ alog, const float* __restrict__ vh,
    const float* __restrict__ vpts, const float* __restrict__ pairz,
    float* __restrict__ featsT) {
    int n = blockIdx.x;
    int t = threadIdx.x;
    __shared__ float red[16 * 12];
    __shared__ float mh[12], linv[12];
    __shared__ float al[CAPE * 12];
    __shared__ int el[CAPE], sl_[CAPE];
    int row0 = rowptr[n];
    int deg = rowptr[n + 1] - row0;
    int g = t >> 4, l16 = t & 15;
    if (l16 < 12) {
        float lm = -1e30f;
        for (int i = g; i < deg; i += 16)
            lm = fmaxf(lm, alog[(long)(row0 + i) * 12 + l16]);
        red[g * 12 + l16] = lm;
    }
    __syncthreads();
    if (t < 12) {
        float m = -1e30f;
        for (int gg = 0; gg < 16; gg++) m = fmaxf(m, red[gg * 12 + t]);
        mh[t] = m;
    }
    __syncthreads();
    if (l16 < 12) {
        float m = mh[l16];
        float ls = 0.f;
        for (int i = g; i < deg; i += 16)
            ls += expf(alog[(long)(row0 + i) * 12 + l16] - m);
        red[g * 12 + l16] = ls;
    }
    __syncthreads();
    if (t < 12) {
        float ssum = 0.f;
        for (int gg = 0; gg < 16; gg++) ssum += red[gg * 12 + t];
        linv[t] = 1.f / (ssum + 1e-16f);
    }

    const float* base = nullptr;
    int scale = 0, hk = 0, use_e = 0;
    int comp = t * 4;
    if (comp < 192)      { base = vh + comp; scale = 192; hk = comp >> 4; }
    else if (comp < 480) { int idx = comp - 192; base = vpts + idx; scale = 288; hk = idx / 24; }
    else if (comp < 864) { int idx = comp - 480; base = pairz + (idx & 31); scale = 32; hk = idx >> 5; use_e = 1; }
    float4 acc = make_float4(0.f, 0.f, 0.f, 0.f);

    for (int cs = 0; cs < deg; cs += CAPE) {
        int cnt = min(CAPE, deg - cs);
        __syncthreads();
        for (int i = t; i < cnt * 12; i += 256) {
            int h = i % 12;
            al[i] = expf(alog[(long)(row0 + cs) * 12 + i] - mh[h]) * linv[h];
        }
        for (int i = t; i < cnt; i += 256) {
            int p = row0 + cs + i;
            el[i] = csr[p];
            sl_[i] = src_csr[p];
        }
        __syncthreads();
        if (t < 216) {
            int i = 0;
            for (; i + 4 <= cnt; i += 4) {
                int i0 = use_e ? el[i] : sl_[i];
                int i1 = use_e ? el[i+1] : sl_[i+1];
                int i2 = use_e ? el[i+2] : sl_[i+2];
                int i3 = use_e ? el[i+3] : sl_[i+3];
                float4 v0 = *(const float4*)(base + (long)i0 * scale);
                float4 v1 = *(const float4*)(base + (long)i1 * scale);
                float4 v2 = *(const float4*)(base + (long)i2 * scale);
                float4 v3 = *(const float4*)(base + (long)i3 * scale);
                float w0 = al[i * 12 + hk];
                float w1 = al[(i+1) * 12 + hk];
                float w2 = al[(i+2) * 12 + hk];
                float w3 = al[(i+3) * 12 + hk];
                acc.x = fmaf(w0, v0.x, acc.x); acc.y = fmaf(w0, v0.y, acc.y);
                acc.z = fmaf(w0, v0.z, acc.z); acc.w = fmaf(w0, v0.w, acc.w);
                acc.x = fmaf(w1, v1.x, acc.x); acc.y = fmaf(w1, v1.y, acc.y);
                acc.z = fmaf(w1, v1.z, acc.z); acc.w = fmaf(w1, v1.w, acc.w);
                acc.x = fmaf(w2, v2.x, acc.x); acc.y = fmaf(w2, v2.y, acc.y);
                acc.z = fmaf(w2, v2.z, acc.z); acc.w = fmaf(w2, v2.w, acc.w);
                acc.x = fmaf(w3, v3.x, acc.x); acc.y = fmaf(w3, v3.y, acc.y);
                acc.z = fmaf(w3, v3.z, acc.z); acc.w = fmaf(w3, v3.w, acc.w);
            }
            for (; i < cnt; i++) {
                int ii = use_e ? el[i] : sl_[i];
                float4 v = *(const float4*)(base + (long)ii * scale);
                float w = al[i * 12 + hk];
                acc.x = fmaf(w, v.x, acc.x); acc.y = fmaf(w, v.y, acc.y);
                acc.z = fmaf(w, v.z, acc.z); acc.w = fmaf(w, v.w, acc.w);
            }
        }
    }
    if (t < 216) {
        float vals[4] = {acc.x, acc.y, acc.z, acc.w};
        #pragma unroll
        for (int u = 0; u < 4; u++) {
            int cmp = t * 4 + u;
            int row;
            if (cmp < 192) row = cmp;
            else if (cmp < 480) { int idx = cmp - 192; int p = idx / 3, i = idx % 3; row = 192 + i * 96 + p; }
            else row = cmp + 96;
            featsT[(long)row * NPAD + n] = vals[u];
        }
    }
}

// ---- inverse-rotate pt rows of featsT in place + write norm rows ----
__global__ __launch_bounds__(256) void k_feat(float* __restrict__ featsT,
    const float* __restrict__ rot, const float* __restrict__ trans) {
    int t = threadIdx.x;
    int lane = t & 63, wv = t >> 6;
    int n = blockIdx.x * 64 + lane;
    bool valid = n < N_RESC;
    int ns = valid ? n : 0;
    float R[9], T[3];
    #pragma unroll
    for (int k = 0; k < 9; k++) R[k] = rot[(long)ns * 9 + k];
    #pragma unroll
    for (int k = 0; k < 3; k++) T[k] = trans[(long)ns * 3 + k];
    for (int p = wv * 24; p < wv * 24 + 24; p++) {
        float gx = featsT[(long)(192 + p) * NPAD + n] - T[0];
        float gy = featsT[(long)(288 + p) * NPAD + n] - T[1];
        float gz = featsT[(long)(384 + p) * NPAD + n] - T[2];
        float lx = R[0]*gx + R[3]*gy + R[6]*gz;
        float ly = R[1]*gx + R[4]*gy + R[7]*gz;
        float lz = R[2]*gx + R[5]*gy + R[8]*gz;
        if (valid) {
            featsT[(long)(192 + p) * NPAD + n] = lx;
            featsT[(long)(288 + p) * NPAD + n] = ly;
            featsT[(long)(384 + p) * NPAD + n] = lz;
            featsT[(long)(480 + p) * NPAD + n] = sqrtf(lx*lx + ly*ly + lz*lz + 1e-8f);
        }
    }
}

// ---- final GEMM: out = featsT^T @ wout + bout; lane=node, uniform weights ----
__global__ __launch_bounds__(256) void k_final_g(const float* __restrict__ featsT,
    const float* __restrict__ wout, const float* __restrict__ bout,
    float* __restrict__ out) {
    int t = threadIdx.x;
    int lane = t & 63;
    int wv = __builtin_amdgcn_readfirstlane(t >> 6);
    int n = blockIdx.x * 64 + lane;
    int c0 = blockIdx.y * 128 + wv * 32;
    float acc[32];
    #pragma unroll
    for (int cc = 0; cc < 32; cc++) acc[cc] = bout[c0 + cc];
    for (int j = 0; j < FEAT_D; j++) {
        float fval = featsT[(long)j * NPAD + n];
        const float* wj = wout + (long)j * OUT_D + c0;
        #pragma unroll
        for (int q = 0; q < 8; q++) {
            float4 w4 = *(const float4*)(wj + q * 4);
            acc[q*4+0] = fmaf(fval, w4.x, acc[q*4+0]);
            acc[q*4+1] = fmaf(fval, w4.y, acc[q*4+1]);
            acc[q*4+2] = fmaf(fval, w4.z, acc[q*4+2]);
            acc[q*4+3] = fmaf(fval, w4.w, acc[q*4+3]);
        }
    }
    if (n < N_RESC) {
        #pragma unroll
        for (int cc = 0; cc < 32; cc++)
            out[(long)n * OUT_D + c0 + cc] = acc[cc];
    }
}

extern "C" void kernel_launch(void* const* d_in, const int* in_sizes, int n_in,
                              void* d_out, int out_size, void* d_ws, size_t ws_size,
                              hipStream_t stream) {
    const float* s     = (const float*)d_in[0];
    const float* z     = (const float*)d_in[1];
    const float* rot   = (const float*)d_in[2];
    const float* trans = (const float*)d_in[3];
    const float* mask  = (const float*)d_in[4];
    const int*   ei    = (const int*)d_in[5];
    const float* wq    = (const float*)d_in[6];
    const float* bq    = (const float*)d_in[7];
    const float* wkv   = (const float*)d_in[8];
    const float* bkv   = (const float*)d_in[9];
    const float* wqp   = (const float*)d_in[10];
    const float* bqp   = (const float*)d_in[11];
    const float* wkvp  = (const float*)d_in[12];
    const float* bkvp  = (const float*)d_in[13];
    const float* wb    = (const float*)d_in[14];
    const float* bb    = (const float*)d_in[15];
    const float* wdz   = (const float*)d_in[16];
    const float* bdz   = (const float*)d_in[17];
    const float* head_w= (const float*)d_in[18];
    const float* wout  = (const float*)d_in[19];
    const float* bout  = (const float*)d_in[20];
    float* out = (float*)d_out;

    float* ws    = (float*)d_ws;
    float* qh    = ws;                          // 1,920,000
    float* kh    = qh + 1920000;                // 1,920,000
    float* vh    = kh + 1920000;                // 1,920,000
    float* qpts  = vh + 1920000;                // 1,440,000
    float* kpts  = qpts + 1440000;              // 1,440,000
    float* vpts  = kpts + 1440000;              // 2,880,000
    float* b_e   = vpts + 2880000;              // 3,840,000
    float* pairz = b_e + 3840000;               // 10,240,000
    float* sT    = pairz;                       // alias: 384*10240=3,932,160 <= 10,240,000 (dead before k_zproj)
    float* alog  = pairz + 10240000;            // 3,840,000
    float* featsT= alog + 3840000;              // 960*10240 = 9,830,400
    float* praw  = featsT;                      // alias: 5,760,000 (dead before k_agg writes featsT)
    float* W_all = featsT + 9830400;            // 442,368
    float* b_all = W_all + 442368;              // 1,152
    int* rowptr  = (int*)(b_all + 1152);        // 10004
    int* cursor  = rowptr + 10004;              // 10000
    int* csr     = cursor + 10000;              // 320,000
    int* src_csr = csr + 320000;                // 320,000

    // CSR build by dst
    k_zero<<<(N_RESC + 255) / 256, 256, 0, stream>>>(cursor);
    k_hist<<<(N_EDGEC + 255) / 256, 256, 0, stream>>>(ei, cursor);
    k_scan<<<1, 1024, 0, stream>>>(cursor, rowptr);
    k_scatter<<<(N_EDGEC + 255) / 256, 256, 0, stream>>>(ei, cursor, csr, src_csr);

    // pack weights + transpose s
    k_pack<<<(384 * 1152 + 255) / 256, 256, 0, stream>>>(wq, wkv, wqp, wkvp,
                                                         bq, bkv, bqp, bkvp, W_all, b_all);
    k_transpose<<<dim3(157, 6), 256, 0, stream>>>(s, sT);

    // node projection GEMM (uniform-weight form)
    k_proj_g<<<dim3(157, 9), 256, 0, stream>>>(sT, W_all, b_all, qh, kh, vh, praw);
    k_rot<<<N_RESC, 192, 0, stream>>>(praw, rot, trans, qpts, kpts, vpts);

    // edge z-projection GEMM (overwrites sT region -- sT dead)
    k_zproj<<<N_EDGEC / 256, 256, 0, stream>>>(z, wb, bb, wdz, bdz, b_e, pairz);

    // logits in CSR order
    k_logit<<<N_RESC, 256, 0, stream>>>(rowptr, csr, src_csr, qh, kh, qpts, kpts,
                                        mask, head_w, b_e, alog);

    // per-node softmax + aggregation -> featsT (overwrites praw -- dead)
    k_agg<<<N_RESC, 256, 0, stream>>>(rowptr, csr, src_csr, alog, vh, vpts, pairz, featsT);

    // in-place inverse rotation + norms
    k_feat<<<157, 256, 0, stream>>>(featsT, rot, trans);

    // final GEMM
    k_final_g<<<dim3(157, 3), 256, 0, stream>>>(featsT, wout, bout, out);
}